// Round 14
// baseline (618.115 us; speedup 1.0000x reference)
//
#include <hip/hip_runtime.h>
#include <hip/hip_bf16.h>
#include <stdint.h>

#define HH 128

typedef __attribute__((ext_vector_type(8))) short short8;
typedef __attribute__((ext_vector_type(4))) float floatx4;

typedef __attribute__((address_space(3))) uint32_t lds_u32_t;
typedef const __attribute__((address_space(1))) uint32_t gbl_u32_t;

__device__ __forceinline__ void gl_lds16(const void* g, void* l) {
  __builtin_amdgcn_global_load_lds((gbl_u32_t*)g, (lds_u32_t*)l, 16, 0, 0);
}

__device__ __forceinline__ float bf2f(short v) {
  union { uint32_t u; float f; } x; x.u = ((uint32_t)(uint16_t)v) << 16; return x.f;
}
__device__ __forceinline__ short f2bf(float f) {
  union { float f; uint32_t u; } x; x.f = f;
  uint32_t r = x.u + 0x7fffu + ((x.u >> 16) & 1u);
  return (short)(r >> 16);
}
__device__ __forceinline__ float rdf(const void* p, int i, int fl) {
  return fl ? bf2f(((const short*)p)[i]) : ((const float*)p)[i];
}
__device__ __forceinline__ uint32_t packbf(float a, float b) {
  return (uint32_t)(uint16_t)f2bf(a) | ((uint32_t)(uint16_t)f2bf(b) << 16);
}

// ---------------- probe + zero kernel ----------------

__global__ void detect_zero(const int* __restrict__ eidx, int* iflag, int* dflag,
                            int* __restrict__ counts, float* accp, int* ticket,
                            const uint32_t* __restrict__ loc, int N) {
  int g = blockIdx.x * 256 + threadIdx.x;
  if (g < N) counts[g] = 0;
  if (blockIdx.x == 0) {
    __shared__ int nz, cnt;
    if (threadIdx.x == 0) { nz = 0; cnt = 0; *accp = 0.f; *ticket = 0; }
    __syncthreads();
    int any = 0;
    for (int i = threadIdx.x; i < 1024; i += 256) any |= (eidx[2 * i + 1] != 0);
    if (any) atomicOr(&nz, 1);
    uint32_t u = loc[threadIdx.x];
    int e = (u >> 7) & 0xFF;
    if (e >= 100 && e <= 140) atomicAdd(&cnt, 1);
    __syncthreads();
    if (threadIdx.x == 0) {
      *iflag = (nz == 0) ? 1 : 0;    // 1 => int64 layout
      *dflag = (cnt >= 192) ? 1 : 0; // 1 => bf16 tensors
    }
  }
}

// ---------------- mega prep: pad + weight-transpose + bias-cvt + fold ----------------
// Segments by block range:
//   [0,B0)   pad_input: (N,64) bf16 padded input
//   [B0,B1)  prep_w: 5 transposed matrices into wbase
//   [B1,B2)  prep_b: fp32 bias table
//   [B2,B3)  fold mats (26 x 128x128, B-layout [n][k]) from RAW weights:
//            m0..6 Wf_l = msgW2_l@updW1b_l; m7..13 Amat_l = updW2_l@M1a_{l+1}
//            (l=6: updW2_6@headW1); m14..19 Bmat_l; m20..25 Cmat_l
//   [B3,B4)  fold bias (26 x 128 fp32): b2U | pA(+msgB1/headB1) | pB | pC(+updB1)

struct MegaArgs {
  const void* loc; const void* vel;
  const void* wsrc[5];
  unsigned long long wdst[5];
  int wK[5], wN[5], wKp[5], wNp[5];
  int wb[6];
  const void* bsrc[8];
  int bn[8];
  int bes[9];
  const void* mW1r; const void* mW2r; const void* uW1r; const void* uW2r; const void* hW1r;
  const void* mB1r; const void* mB2r; const void* uB1r; const void* uB2r; const void* hB1r;
  int B0, B1, B2, B3;
};

__global__ void mega_prep(MegaArgs a, short* __restrict__ wbase, float* __restrict__ bias,
                          short* __restrict__ in64, short* __restrict__ fmats,
                          float* __restrict__ fbias, const int* __restrict__ dflag) {
  int fl = *dflag;
  int b = blockIdx.x, tid = threadIdx.x;
  if (b < a.B0) {
    int idx = b * 256 + tid;
    int j = idx & 63, i = idx >> 6;
    short v = 0;
    if (j < 60) {
      int f = j / 6, c = j % 6;
      float x = (c < 3) ? rdf(a.loc, (i * 10 + f) * 3 + c, fl)
                        : rdf(a.vel, (i * 10 + f) * 3 + (c - 3), fl);
      v = f2bf(x);
    }
    in64[idx] = v;
  } else if (b < a.B1) {
    int rb = b - a.B0;
    int s = 0;
    while (rb >= a.wb[s + 1]) ++s;
    int idx = (rb - a.wb[s]) * 256 + tid;
    int Kp = a.wKp[s], Np = a.wNp[s], K = a.wK[s], Nn = a.wN[s];
    if (idx < Np * Kp) {
      int k = idx % Kp, n = idx / Kp;
      short v = 0;
      if (k < K && n < Nn) v = f2bf(rdf(a.wsrc[s], k * Nn + n, fl));
      wbase[a.wdst[s] + idx] = v;
    }
  } else if (b < a.B2) {
    int idx = (b - a.B1) * 256 + tid;
    if (idx < a.bes[8]) {
      int s = 0;
      while (idx >= a.bes[s + 1]) ++s;
      int j = idx - a.bes[s];
      bias[idx] = (j < a.bn[s]) ? rdf(a.bsrc[s], j, fl) : 0.0f;
    }
  } else if (b < a.B3) {
    int idx = (b - a.B2) * 256 + tid;
    if (idx < 26 * 16384) {
      int k = idx & 127, n = (idx >> 7) & 127, m = idx >> 14;
      float s = 0.f;
      if (m < 7) {
        for (int j = 0; j < 128; ++j)
          s += rdf(a.mW2r, (m * 128 + k) * 128 + j, fl) *
               rdf(a.uW1r, (m * 256 + 128 + j) * 128 + n, fl);
      } else if (m < 14) {
        int l = m - 7;
        if (l < 6) {
          for (int j = 0; j < 128; ++j)
            s += rdf(a.uW2r, (l * 128 + k) * 128 + j, fl) *
                 rdf(a.mW1r, ((l + 1) * 256 + j) * 128 + n, fl);
        } else {
          for (int j = 0; j < 128; ++j)
            s += rdf(a.uW2r, (6 * 128 + k) * 128 + j, fl) *
                 rdf(a.hW1r, j * 128 + n, fl);
        }
      } else if (m < 20) {
        int l = m - 14;
        for (int j = 0; j < 128; ++j)
          s += rdf(a.uW2r, (l * 128 + k) * 128 + j, fl) *
               rdf(a.mW1r, ((l + 1) * 256 + 128 + j) * 128 + n, fl);
      } else {
        int l = m - 20;
        for (int j = 0; j < 128; ++j)
          s += rdf(a.uW2r, (l * 128 + k) * 128 + j, fl) *
               rdf(a.uW1r, ((l + 1) * 256 + j) * 128 + n, fl);
      }
      fmats[idx] = f2bf(s);
    }
  } else {
    int idx = (b - a.B3) * 256 + tid;
    if (idx < 26 * 128) {
      int n = idx & 127, m = idx >> 7;
      float s = 0.f;
      if (m < 7) {
        for (int j = 0; j < 128; ++j)
          s += rdf(a.mB2r, m * 128 + j, fl) * rdf(a.uW1r, (m * 256 + 128 + j) * 128 + n, fl);
      } else if (m < 14) {
        int l = m - 7;
        if (l < 6) {
          for (int j = 0; j < 128; ++j)
            s += rdf(a.uB2r, l * 128 + j, fl) * rdf(a.mW1r, ((l + 1) * 256 + j) * 128 + n, fl);
          s += rdf(a.mB1r, (l + 1) * 128 + n, fl);
        } else {
          for (int j = 0; j < 128; ++j)
            s += rdf(a.uB2r, 6 * 128 + j, fl) * rdf(a.hW1r, j * 128 + n, fl);
          s += rdf(a.hB1r, n, fl);
        }
      } else if (m < 20) {
        int l = m - 14;
        for (int j = 0; j < 128; ++j)
          s += rdf(a.uB2r, l * 128 + j, fl) * rdf(a.mW1r, ((l + 1) * 256 + 128 + j) * 128 + n, fl);
      } else {
        int l = m - 20;
        for (int j = 0; j < 128; ++j)
          s += rdf(a.uB2r, l * 128 + j, fl) * rdf(a.uW1r, ((l + 1) * 256 + j) * 128 + n, fl);
        s += rdf(a.uB1r, (l + 1) * 128 + n, fl);
      }
      fbias[m * 128 + n] = s;
    }
  }
}

// ---------------- edge sort (counting sort by dst) ----------------

__global__ void hist_kernel(const int* __restrict__ eidx, const int* __restrict__ iflag,
                            int* __restrict__ counts, int E) {
  int e = blockIdx.x * 256 + threadIdx.x;
  if (e >= E) return;
  int fl = *iflag;
  int d = fl ? eidx[2 * (E + e)] : eidx[E + e];
  atomicAdd(&counts[d], 1);
}

__global__ void scan_bsum(const int* __restrict__ counts, int* __restrict__ bsums, int N) {
  int i = blockIdx.x * 256 + threadIdx.x;
  int v = (i < N) ? counts[i] : 0;
#pragma unroll
  for (int off = 1; off < 64; off <<= 1) v += __shfl_xor(v, off);
  __shared__ int ws4[4];
  if ((threadIdx.x & 63) == 0) ws4[threadIdx.x >> 6] = v;
  __syncthreads();
  if (threadIdx.x == 0) bsums[blockIdx.x] = ws4[0] + ws4[1] + ws4[2] + ws4[3];
}

__global__ void scan_final(const int* __restrict__ counts, const int* __restrict__ bsums,
                           int* __restrict__ row_start, int* __restrict__ cursor,
                           float* __restrict__ deg, int N, int E) {
  int t = threadIdx.x;
  __shared__ int shb[2];
  __shared__ int wsum[4];
  int v = (t < 128 && t < (int)blockIdx.x) ? bsums[t] : 0;
#pragma unroll
  for (int off = 1; off < 64; off <<= 1) v += __shfl_xor(v, off);
  if (t == 0) shb[0] = v;
  if (t == 64) shb[1] = v;
  int i = blockIdx.x * 256 + t;
  int c = (i < N) ? counts[i] : 0;
  int lane = t & 63, w = t >> 6;
  int x = c;
#pragma unroll
  for (int off = 1; off < 64; off <<= 1) {
    int u = __shfl_up(x, off);
    if (lane >= off) x += u;
  }
  if (lane == 63) wsum[w] = x;
  __syncthreads();
  int wpre = 0;
#pragma unroll
  for (int k = 0; k < 4; ++k)
    if (k < w) wpre += wsum[k];
  int excl = shb[0] + shb[1] + wpre + x - c;
  if (i < N) {
    row_start[i] = excl;
    cursor[i] = excl;
    deg[i] = (float)c;
  }
  if (i == N - 1) row_start[N] = E;
}

__global__ void scatter_kernel(const int* __restrict__ eidx, const int* __restrict__ iflag,
                               int* __restrict__ cursor, int* __restrict__ ssrc, int E) {
  int e = blockIdx.x * 256 + threadIdx.x;
  if (e >= E) return;
  int fl = *iflag;
  int d = fl ? eidx[2 * (E + e)] : eidx[E + e];
  int sv = fl ? eidx[2 * e] : eidx[e];
  int pos = atomicAdd(&cursor[d], 1);
  ssrc[pos] = sv;
}

// ---------------- edge aggregation: Hagg[d] = sum relu(P[d] + Q[src]) ----------------

__global__ __launch_bounds__(256)
void edge_agg(const uint32_t* __restrict__ Pp, const uint32_t* __restrict__ Qp,
              const int* __restrict__ ssrc, const int* __restrict__ row_start,
              uint32_t* __restrict__ Hagg, int Ntot) {
  int w = threadIdx.x >> 6, lane = threadIdx.x & 63;
  int d = blockIdx.x * 4 + w;
  if (d >= Ntot) return;
  uint32_t pv = Pp[(size_t)d * 64 + lane];
  float px = bf2f((short)(pv & 0xffff));
  float py = bf2f((short)(pv >> 16));
  int s0 = row_start[d], s1 = row_start[d + 1];
  float ax = 0.f, ay = 0.f;
  int e = s0;
  for (; e + 16 <= s1; e += 16) {
    int idx[16]; uint32_t q[16];
#pragma unroll
    for (int u = 0; u < 16; ++u) idx[u] = ssrc[e + u];
#pragma unroll
    for (int u = 0; u < 16; ++u) q[u] = Qp[(size_t)idx[u] * 64 + lane];
#pragma unroll
    for (int u = 0; u < 16; ++u) {
      float hx = px + bf2f((short)(q[u] & 0xffff));
      float hy = py + bf2f((short)(q[u] >> 16));
      ax += hx > 0.f ? hx : 0.f;
      ay += hy > 0.f ? hy : 0.f;
    }
  }
  if (e + 8 <= s1) {
    int idx[8]; uint32_t q[8];
#pragma unroll
    for (int u = 0; u < 8; ++u) idx[u] = ssrc[e + u];
#pragma unroll
    for (int u = 0; u < 8; ++u) q[u] = Qp[(size_t)idx[u] * 64 + lane];
#pragma unroll
    for (int u = 0; u < 8; ++u) {
      float hx = px + bf2f((short)(q[u] & 0xffff));
      float hy = py + bf2f((short)(q[u] >> 16));
      ax += hx > 0.f ? hx : 0.f;
      ay += hy > 0.f ? hy : 0.f;
    }
    e += 8;
  }
  if (e + 4 <= s1) {
    int idx[4]; uint32_t q[4];
#pragma unroll
    for (int u = 0; u < 4; ++u) idx[u] = ssrc[e + u];
#pragma unroll
    for (int u = 0; u < 4; ++u) q[u] = Qp[(size_t)idx[u] * 64 + lane];
#pragma unroll
    for (int u = 0; u < 4; ++u) {
      float hx = px + bf2f((short)(q[u] & 0xffff));
      float hy = py + bf2f((short)(q[u] >> 16));
      ax += hx > 0.f ? hx : 0.f;
      ay += hy > 0.f ? hy : 0.f;
    }
    e += 4;
  }
  if (e + 2 <= s1) {
    int i0 = ssrc[e], i1 = ssrc[e + 1];
    uint32_t q0 = Qp[(size_t)i0 * 64 + lane];
    uint32_t q1 = Qp[(size_t)i1 * 64 + lane];
    float hx = px + bf2f((short)(q0 & 0xffff)), hy = py + bf2f((short)(q0 >> 16));
    ax += hx > 0.f ? hx : 0.f; ay += hy > 0.f ? hy : 0.f;
    hx = px + bf2f((short)(q1 & 0xffff)); hy = py + bf2f((short)(q1 >> 16));
    ax += hx > 0.f ? hx : 0.f; ay += hy > 0.f ? hy : 0.f;
    e += 2;
  }
  if (e < s1) {
    int i0 = ssrc[e];
    uint32_t q0 = Qp[(size_t)i0 * 64 + lane];
    float hx = px + bf2f((short)(q0 & 0xffff));
    float hy = py + bf2f((short)(q0 >> 16));
    ax += hx > 0.f ? hx : 0.f;
    ay += hy > 0.f ? hy : 0.f;
  }
  Hagg[(size_t)d * 64 + lane] = packbf(ax, ay);
}

// ---------------- fused MLP helpers (M=64, 4 waves, 48 KB LDS) ----------------

__device__ __forceinline__ void write_aslots64(char* lds, const floatx4 v[2][4],
                                               int wr, int wc, int quad, int l16) {
#pragma unroll
  for (int mt = 0; mt < 2; ++mt) {
    int g = wr * 2 + mt;
#pragma unroll
    for (int nt = 0; nt < 4; ++nt) {
      int s2 = wc * 2 + (nt >> 1);
      int qc = (nt & 1) * 2 + (l16 >> 3);
      char* base = lds + (size_t)(s2 * 4 + g) * 1024 + 2 * (l16 & 7);
#pragma unroll
      for (int r = 0; r < 4; ++r)
        *(short*)(base + (quad * 4 + r + 16 * qc) * 16) = f2bf(v[mt][nt][r]);
    }
  }
}

template <int NT, int TS>
__device__ __forceinline__ void gemm64(const char* lds, int wr, int wc,
                                       floatx4 acc[2][NT], int lane) {
  const char* ldsB = lds + 16384;
#pragma unroll
  for (int s2 = 0; s2 < 4; ++s2) {
    short8 af[2];
#pragma unroll
    for (int mt = 0; mt < 2; ++mt)
      af[mt] = *(const short8*)(lds + (s2 * 4 + wr * 2 + mt) * 1024 + lane * 16);
    short8 bf[NT];
#pragma unroll
    for (int nt = 0; nt < NT; ++nt)
      bf[nt] = *(const short8*)(ldsB + (s2 * TS + wc * NT + nt) * 1024 + lane * 16);
#pragma unroll
    for (int mt = 0; mt < 2; ++mt)
#pragma unroll
      for (int nt = 0; nt < NT; ++nt)
        acc[mt][nt] = __builtin_amdgcn_mfma_f32_16x16x32_bf16(af[mt], bf[nt], acc[mt][nt], 0, 0, 0);
  }
}

__device__ __forceinline__ void stage128(const short* M, int stride, char* ldsB,
                                         int w, int lane, int quad, int l16) {
#pragma unroll
  for (int c = 0; c < 8; ++c) {
    int slot = w * 8 + c, s2 = slot >> 3, t = slot & 7;
    gl_lds16(M + (t * 16 + l16) * stride + s2 * 32 + quad * 8,
             ldsB + slot * 1024 + lane * 16);
  }
}

// ---------------- fused MLP kernel ----------------
// MODE 0: embed (in64 -> x0 in regs) then P0/Q0/XU0
// MODE 2: h = relu(XU + Hagg@Wf + deg*b2U) then P/Q/XU via folded mats
// MODE 3: h (layer 6) then head MLP -> out32

template <int MODE>
__global__ __launch_bounds__(256, 3)
void mlp_fused(const short* __restrict__ Ain, const short* __restrict__ XUin,
               const short* __restrict__ W1s, const float* __restrict__ b1s,
               const short* __restrict__ W2s, const float* __restrict__ b2s,
               const short* __restrict__ W3s, const float* __restrict__ b3s,
               const short* __restrict__ W4s, const float* __restrict__ b4s,
               const float* __restrict__ deg,
               short* __restrict__ Pout, short* __restrict__ Qout,
               short* __restrict__ XUout, float* __restrict__ out32) {
  __shared__ __align__(16) char lds[49152];
  char* ldsB = lds + 16384;

  const int tid = threadIdx.x;
  const int w = tid >> 6, lane = tid & 63;
  const int quad = lane >> 4, l16 = lane & 15;
  const int wr = w >> 1, wc = w & 1;
  const int R0 = blockIdx.x * 64;
  const int CB = wc * 64;

  floatx4 zero4 = {0.f, 0.f, 0.f, 0.f};
  floatx4 acc[2][4];

  if constexpr (MODE == 0) {
#pragma unroll
    for (int c = 0; c < 4; ++c) {
      int slot = w * 4 + c, s = slot >> 3, t = slot & 7;
      gl_lds16(W1s + (t * 16 + l16) * 64 + s * 32 + quad * 8,
               ldsB + slot * 1024 + lane * 16);
    }
    short8 afrag[2][2];
#pragma unroll
    for (int mt = 0; mt < 2; ++mt) {
      int m = R0 + wr * 32 + mt * 16 + l16;
      const short* pr = Ain + (size_t)m * 64;
#pragma unroll
      for (int s = 0; s < 2; ++s) afrag[s][mt] = *(const short8*)(pr + s * 32 + quad * 8);
    }
    float b1f[4], b2f[4], pa[4], pc[4];
#pragma unroll
    for (int t = 0; t < 4; ++t) {
      int col = CB + t * 16 + l16;
      b1f[t] = b1s[col]; b2f[t] = b2s[col]; pa[t] = b3s[col]; pc[t] = b4s[col];
    }
#pragma unroll
    for (int mt = 0; mt < 2; ++mt)
#pragma unroll
      for (int t = 0; t < 4; ++t) acc[mt][t] = zero4;
    __syncthreads();  // B1
#pragma unroll
    for (int s = 0; s < 2; ++s) {
      short8 bfrag[4];
#pragma unroll
      for (int nt = 0; nt < 4; ++nt)
        bfrag[nt] = *(const short8*)(ldsB + (s * 8 + wc * 4 + nt) * 1024 + lane * 16);
#pragma unroll
      for (int mt = 0; mt < 2; ++mt)
#pragma unroll
        for (int nt = 0; nt < 4; ++nt)
          acc[mt][nt] = __builtin_amdgcn_mfma_f32_16x16x32_bf16(afrag[s][mt], bfrag[nt], acc[mt][nt], 0, 0, 0);
    }
    __syncthreads();  // B2
    stage128(W2s, 128, ldsB, w, lane, quad, l16);  // embW2
    {
      floatx4 hv[2][4];
#pragma unroll
      for (int mt = 0; mt < 2; ++mt)
#pragma unroll
        for (int nt = 0; nt < 4; ++nt)
#pragma unroll
          for (int r = 0; r < 4; ++r) {
            float h = acc[mt][nt][r] + b1f[nt];
            hv[mt][nt][r] = h > 0.f ? h : 0.f;
          }
      write_aslots64(lds, hv, wr, wc, quad, l16);
    }
    __syncthreads();  // B3
    floatx4 accx[2][4];
#pragma unroll
    for (int mt = 0; mt < 2; ++mt)
#pragma unroll
      for (int t = 0; t < 4; ++t) accx[mt][t] = zero4;
    gemm64<4, 8>(lds, wr, wc, accx, lane);
    floatx4 xv[2][4];
#pragma unroll
    for (int mt = 0; mt < 2; ++mt)
#pragma unroll
      for (int nt = 0; nt < 4; ++nt)
#pragma unroll
        for (int r = 0; r < 4; ++r)
          xv[mt][nt][r] = accx[mt][nt][r] + b2f[nt];
    __syncthreads();  // B4
    write_aslots64(lds, xv, wr, wc, quad, l16);
    stage128(W3s, 256, ldsB, w, lane, quad, l16);  // M1a_0
    __syncthreads();  // B5
    floatx4 ap[2][4];
#pragma unroll
    for (int mt = 0; mt < 2; ++mt)
#pragma unroll
      for (int t = 0; t < 4; ++t) ap[mt][t] = zero4;
    gemm64<4, 8>(lds, wr, wc, ap, lane);
#pragma unroll
    for (int mt = 0; mt < 2; ++mt)
#pragma unroll
      for (int nt = 0; nt < 4; ++nt) {
        int col = CB + nt * 16 + l16;
#pragma unroll
        for (int r = 0; r < 4; ++r) {
          int row = R0 + wr * 32 + mt * 16 + quad * 4 + r;
          Pout[(size_t)row * HH + col] = f2bf(ap[mt][nt][r] + pa[nt]);
        }
      }
    __syncthreads();  // B6
    stage128(W3s + 128, 256, ldsB, w, lane, quad, l16);  // M1b_0
    __syncthreads();  // B7
    floatx4 aq[2][4];
#pragma unroll
    for (int mt = 0; mt < 2; ++mt)
#pragma unroll
      for (int t = 0; t < 4; ++t) aq[mt][t] = zero4;
    gemm64<4, 8>(lds, wr, wc, aq, lane);
#pragma unroll
    for (int mt = 0; mt < 2; ++mt)
#pragma unroll
      for (int nt = 0; nt < 4; ++nt) {
        int col = CB + nt * 16 + l16;
#pragma unroll
        for (int r = 0; r < 4; ++r) {
          int row = R0 + wr * 32 + mt * 16 + quad * 4 + r;
          Qout[(size_t)row * HH + col] = f2bf(aq[mt][nt][r]);
        }
      }
    __syncthreads();  // B8
    stage128(W4s, 256, ldsB, w, lane, quad, l16);  // U1a_0
    __syncthreads();  // B9
    floatx4 au[2][4];
#pragma unroll
    for (int mt = 0; mt < 2; ++mt)
#pragma unroll
      for (int t = 0; t < 4; ++t) au[mt][t] = zero4;
    gemm64<4, 8>(lds, wr, wc, au, lane);
#pragma unroll
    for (int mt = 0; mt < 2; ++mt)
#pragma unroll
      for (int nt = 0; nt < 4; ++nt) {
        int col = CB + nt * 16 + l16;
#pragma unroll
        for (int r = 0; r < 4; ++r) {
          int row = R0 + wr * 32 + mt * 16 + quad * 4 + r;
          XUout[(size_t)row * HH + col] = f2bf(au[mt][nt][r] + pc[nt]);
        }
      }
    return;
  } else {
    // --- stage Wf; Hagg frags; acc init = XU + deg*b2U ---
    stage128(W1s, 128, ldsB, w, lane, quad, l16);
    short8 hfrag[4][2];
#pragma unroll
    for (int mt = 0; mt < 2; ++mt) {
      int m = R0 + wr * 32 + mt * 16 + l16;
      const short* pr = Ain + (size_t)m * HH;
#pragma unroll
      for (int s = 0; s < 4; ++s) hfrag[s][mt] = *(const short8*)(pr + s * 32 + quad * 8);
    }
    float b2u[4], pa[4], pb[4], pc[4];
#pragma unroll
    for (int t = 0; t < 4; ++t) {
      int col = CB + t * 16 + l16;
      b2u[t] = b1s[col];
      pa[t] = b2s[col];
      if constexpr (MODE == 2) { pb[t] = b3s[col]; pc[t] = b4s[col]; }
    }
    float dvals[2][4];
#pragma unroll
    for (int mt = 0; mt < 2; ++mt)
#pragma unroll
      for (int r = 0; r < 4; ++r)
        dvals[mt][r] = deg[R0 + wr * 32 + mt * 16 + quad * 4 + r];
#pragma unroll
    for (int mt = 0; mt < 2; ++mt)
#pragma unroll
      for (int nt = 0; nt < 4; ++nt) {
        int col = CB + nt * 16 + l16;
#pragma unroll
        for (int r = 0; r < 4; ++r) {
          int row = R0 + wr * 32 + mt * 16 + quad * 4 + r;
          acc[mt][nt][r] = bf2f(XUin[(size_t)row * HH + col]) + dvals[mt][r] * b2u[nt];
        }
      }
    __syncthreads();  // B1
    // GEMM1: Hagg @ Wf
#pragma unroll
    for (int s = 0; s < 4; ++s) {
      short8 bfrag[4];
#pragma unroll
      for (int nt = 0; nt < 4; ++nt)
        bfrag[nt] = *(const short8*)(ldsB + (s * 8 + wc * 4 + nt) * 1024 + lane * 16);
#pragma unroll
      for (int mt = 0; mt < 2; ++mt)
#pragma unroll
        for (int nt = 0; nt < 4; ++nt)
          acc[mt][nt] = __builtin_amdgcn_mfma_f32_16x16x32_bf16(hfrag[s][mt], bfrag[nt], acc[mt][nt], 0, 0, 0);
    }
    __syncthreads();  // B2
    stage128(W2s, 128, ldsB, w, lane, quad, l16);  // Amat
    {
      floatx4 hv[2][4];
#pragma unroll
      for (int mt = 0; mt < 2; ++mt)
#pragma unroll
        for (int nt = 0; nt < 4; ++nt)
#pragma unroll
          for (int r = 0; r < 4; ++r) {
            float h = acc[mt][nt][r];
            hv[mt][nt][r] = h > 0.f ? h : 0.f;
          }
      write_aslots64(lds, hv, wr, wc, quad, l16);
    }
    __syncthreads();  // B3
    floatx4 ap[2][4];
#pragma unroll
    for (int mt = 0; mt < 2; ++mt)
#pragma unroll
      for (int t = 0; t < 4; ++t) ap[mt][t] = zero4;
    gemm64<4, 8>(lds, wr, wc, ap, lane);

    if constexpr (MODE == 2) {
      // P
#pragma unroll
      for (int mt = 0; mt < 2; ++mt)
#pragma unroll
        for (int nt = 0; nt < 4; ++nt) {
          int col = CB + nt * 16 + l16;
#pragma unroll
          for (int r = 0; r < 4; ++r) {
            int row = R0 + wr * 32 + mt * 16 + quad * 4 + r;
            Pout[(size_t)row * HH + col] = f2bf(ap[mt][nt][r] + pa[nt]);
          }
        }
      __syncthreads();  // B4
      stage128(W3s, 128, ldsB, w, lane, quad, l16);  // Bmat
      __syncthreads();  // B5
      floatx4 aq[2][4];
#pragma unroll
      for (int mt = 0; mt < 2; ++mt)
#pragma unroll
        for (int t = 0; t < 4; ++t) aq[mt][t] = zero4;
      gemm64<4, 8>(lds, wr, wc, aq, lane);
#pragma unroll
      for (int mt = 0; mt < 2; ++mt)
#pragma unroll
        for (int nt = 0; nt < 4; ++nt) {
          int col = CB + nt * 16 + l16;
#pragma unroll
          for (int r = 0; r < 4; ++r) {
            int row = R0 + wr * 32 + mt * 16 + quad * 4 + r;
            Qout[(size_t)row * HH + col] = f2bf(aq[mt][nt][r] + pb[nt]);
          }
        }
      __syncthreads();  // B6
      stage128(W4s, 128, ldsB, w, lane, quad, l16);  // Cmat
      __syncthreads();  // B7
      floatx4 au[2][4];
#pragma unroll
      for (int mt = 0; mt < 2; ++mt)
#pragma unroll
        for (int t = 0; t < 4; ++t) au[mt][t] = zero4;
      gemm64<4, 8>(lds, wr, wc, au, lane);
#pragma unroll
      for (int mt = 0; mt < 2; ++mt)
#pragma unroll
        for (int nt = 0; nt < 4; ++nt) {
          int col = CB + nt * 16 + l16;
#pragma unroll
          for (int r = 0; r < 4; ++r) {
            int row = R0 + wr * 32 + mt * 16 + quad * 4 + r;
            XUout[(size_t)row * HH + col] = f2bf(au[mt][nt][r] + pc[nt]);
          }
        }
    } else {
      // MODE 3: head hidden = relu(ap + pa6)
      floatx4 h2[2][4];
#pragma unroll
      for (int mt = 0; mt < 2; ++mt)
#pragma unroll
        for (int nt = 0; nt < 4; ++nt)
#pragma unroll
          for (int r = 0; r < 4; ++r) {
            float h = ap[mt][nt][r] + pa[nt];
            h2[mt][nt][r] = h > 0.f ? h : 0.f;
          }
      __syncthreads();  // B4
      write_aslots64(lds, h2, wr, wc, quad, l16);
#pragma unroll
      for (int c = 0; c < 2; ++c) {
        int slot = w * 2 + c, s2 = slot >> 1, t = slot & 1;
        gl_lds16(W3s + (t * 16 + l16) * 128 + s2 * 32 + quad * 8,
                 ldsB + slot * 1024 + lane * 16);
      }
      __syncthreads();  // B5
      floatx4 acco[2][1];
#pragma unroll
      for (int mt = 0; mt < 2; ++mt) acco[mt][0] = zero4;
      gemm64<1, 2>(lds, wr, wc, acco, lane);
      float ob = b3s[wc * 16 + l16];
#pragma unroll
      for (int mt = 0; mt < 2; ++mt) {
        int col = wc * 16 + l16;
#pragma unroll
        for (int r = 0; r < 4; ++r) {
          int row = R0 + wr * 32 + mt * 16 + quad * 4 + r;
          out32[(size_t)row * 32 + col] = acco[mt][0][r] + ob;
        }
      }
    }
  }
}

// ---------------- loss (fused final reduction via ticket) ----------------

__global__ void loss_kernel(const float* __restrict__ out32, const void* __restrict__ loc,
                            const void* __restrict__ yv, const int* __restrict__ dflag,
                            float* __restrict__ out, float* __restrict__ acc,
                            int* __restrict__ ticket, int NB, int nblocks, float inv) {
  int fl = *dflag;
  int i = blockIdx.x * 256 + threadIdx.x;
  const float* o = out32 + (size_t)i * 32;
  float dsum = 0.f, fde = 0.f;
#pragma unroll
  for (int f = 0; f < 10; ++f) {
    float dx = o[f * 3 + 0] + rdf(loc, i * 30 + f * 3 + 0, fl) - rdf(yv, i * 30 + f * 3 + 0, fl);
    float dy = o[f * 3 + 1] + rdf(loc, i * 30 + f * 3 + 1, fl) - rdf(yv, i * 30 + f * 3 + 1, fl);
    float dz = o[f * 3 + 2] + rdf(loc, i * 30 + f * 3 + 2, fl) - rdf(yv, i * 30 + f * 3 + 2, fl);
    float d = sqrtf(dx * dx + dy * dy + dz * dz);
    dsum += d;
    if (f == 9) fde = d;
  }
#pragma unroll
  for (int m = 1; m < 16; m <<= 1) {
    dsum += __shfl_xor(dsum, m);
    fde += __shfl_xor(fde, m);
  }
  if ((threadIdx.x & 15) == 0) {
    int b = i >> 4;
    out[1 + b] = dsum / 160.0f;
    out[1 + NB + b] = fde / 16.0f;
    unsafeAtomicAdd(acc, dsum);
  }
  __threadfence();
  __syncthreads();
  if (threadIdx.x == 0) {
    int old = atomicAdd(ticket, 1);
    if (old == nblocks - 1) {
      float v = unsafeAtomicAdd(acc, 0.0f);
      out[0] = v * inv;
    }
  }
}

// ---------------- host ----------------

extern "C" void kernel_launch(void* const* d_in, const int* in_sizes, int n_in,
                              void* d_out, int out_size, void* d_ws, size_t ws_size,
                              hipStream_t stream) {
  const void* loc = d_in[0];
  const void* vel = d_in[1];
  const void* yv = d_in[2];
  const int* eidx = (const int*)d_in[3];

  const int N = in_sizes[0] / 30;  // 32768
  const int E = in_sizes[3] / 2;   // 524288
  const int L = 7;
  const int NB = N / 16;

  const size_t MB = 1024 * 1024;
  char* ws = (char*)d_ws;
  short* XU = (short*)ws;                    // N*128 bf16   [0,8)MB
  short* P = (short*)(ws + 8 * MB);          // N*128 bf16
  short* Qs = (short*)(ws + 24 * MB);        // N*128 bf16
  short* Hagg = (short*)(ws + 32 * MB);      // N*128 bf16
  short* fmats = (short*)(ws + 40 * MB);     // 26*16384 bf16
  int* bsums = (int*)(ws + 41 * MB);
  short* wbase = (short*)(ws + 48 * MB);     // 94208 shorts
  const unsigned long long OFF_EMBW1 = 0;       // 128x64
  const unsigned long long OFF_EMBW2 = 8192;    // 128x128
  const unsigned long long OFF_HEADW2 = 24576;  // 32x128
  const unsigned long long OFF_MSGW1 = 28672;   // layer0 128x256
  const unsigned long long OFF_UPDW1 = 61440;   // layer0 128x256
  short* embW1T = wbase + OFF_EMBW1;
  short* embW2T = wbase + OFF_EMBW2;
  short* headW2T = wbase + OFF_HEADW2;
  short* msgW1T = wbase + OFF_MSGW1;
  short* updW1T = wbase + OFF_UPDW1;
  float* bias = (float*)(ws + 49 * MB + 512 * 1024);
  float* embB1f = bias;
  float* embB2f = bias + 128;
  float* msgB1f = bias + 256;
  float* updB1f = bias + 2048;
  float* headB2f = bias + 3968;
  float* fbias = (float*)(ws + 49 * MB + 640 * 1024);  // 26*128 fp32
  int* counts = (int*)(ws + 49 * MB + 768 * 1024);
  int* row_start = (int*)(ws + 50 * MB);
  int* cursor = (int*)(ws + 50 * MB + 256 * 1024);
  float* deg = (float*)(ws + 50 * MB + 512 * 1024);
  int* iflag = (int*)(ws + 50 * MB + 768 * 1024);
  int* dflag = iflag + 16;
  float* accp = (float*)(iflag + 32);
  int* ticket = iflag + 48;
  int* ssrc = (int*)(ws + 51 * MB);
  short* in64 = (short*)(ws + 53 * MB);
  float* out32 = (float*)(ws + 57 * MB);

  const int NBLK = (N + 255) / 256;  // 128

  detect_zero<<<NBLK, 256, 0, stream>>>(eidx, iflag, dflag, counts, accp, ticket,
                                        (const uint32_t*)loc, N);

  // mega prep: pad + transpose + bias + fold (from raw inputs)
  {
    MegaArgs a;
    a.loc = loc; a.vel = vel;
    const void* wsrcs[5] = {d_in[5], d_in[7], d_in[19], d_in[9], d_in[13]};
    unsigned long long wdsts[5] = {OFF_EMBW1, OFF_EMBW2, OFF_HEADW2, OFF_MSGW1, OFF_UPDW1};
    int wKs[5] = {60, 128, 128, 256, 256};
    int wNs[5] = {128, 128, 30, 128, 128};
    int wKps[5] = {64, 128, 128, 256, 256};
    int wNps[5] = {128, 128, 32, 128, 128};
    int cum = 0;
    for (int s = 0; s < 5; ++s) {
      a.wsrc[s] = wsrcs[s]; a.wdst[s] = wdsts[s];
      a.wK[s] = wKs[s]; a.wN[s] = wNs[s]; a.wKp[s] = wKps[s]; a.wNp[s] = wNps[s];
      a.wb[s] = cum;
      cum += (wNps[s] * wKps[s] + 255) / 256;
    }
    a.wb[5] = cum;  // 368
    const void* bsrcs[8] = {d_in[6], d_in[8], d_in[10], d_in[12],
                            d_in[14], d_in[16], d_in[18], d_in[20]};
    int bns[8] = {128, 128, 896, 896, 896, 896, 128, 30};
    int bess[9] = {0, 128, 256, 1152, 2048, 2944, 3840, 3968, 4000};
    for (int s = 0; s < 8; ++s) { a.bsrc[s] = bsrcs[s]; a.bn[s] = bns[s]; a.bes[s] = bess[s]; }
    a.bes[8] = bess[8];
    a.mW1r = d_in[9]; a.mW2r = d_in[11]; a.uW1r = d_in[13]; a.uW2r = d_in[15]; a.hW1r = d_in[17];
    a.mB1r = d_in[10]; a.mB2r = d_in[12]; a.uB1r = d_in[14]; a.uB2r = d_in[16]; a.hB1r = d_in[18];
    a.B0 = (N * 64) / 256;        // 8192
    a.B1 = a.B0 + cum;            // +368
    a.B2 = a.B1 + 16;             // prep_b
    a.B3 = a.B2 + 1664;           // fold mats
    int Btot = a.B3 + 13;         // fold bias
    mega_prep<<<Btot, 256, 0, stream>>>(a, wbase, bias, in64, fmats, fbias, dflag);
  }

  hist_kernel<<<(E + 255) / 256, 256, 0, stream>>>(eidx, iflag, counts, E);
  scan_bsum<<<NBLK, 256, 0, stream>>>(counts, bsums, N);
  scan_final<<<NBLK, 256, 0, stream>>>(counts, bsums, row_start, cursor, deg, N, E);
  scatter_kernel<<<(E + 255) / 256, 256, 0, stream>>>(eidx, iflag, cursor, ssrc, E);

  // embed -> P0/Q0/XU0
  mlp_fused<0><<<N / 64, 256, 0, stream>>>(in64, nullptr,
      embW1T, embB1f, embW2T, embB2f,
      msgW1T, msgB1f, updW1T, updB1f,
      nullptr, P, Qs, XU, nullptr);

  for (int l = 0; l < L; ++l) {
    edge_agg<<<(N + 3) / 4, 256, 0, stream>>>((const uint32_t*)P, (const uint32_t*)Qs,
                                              ssrc, row_start, (uint32_t*)Hagg, N);
    if (l < L - 1) {
      mlp_fused<2><<<N / 64, 256, 0, stream>>>(Hagg, XU,
          fmats + l * 16384, fbias + l * 128,                  // Wf, b2U
          fmats + (7 + l) * 16384, fbias + (7 + l) * 128,      // Amat, pA
          fmats + (14 + l) * 16384, fbias + (14 + l) * 128,    // Bmat, pB
          fmats + (20 + l) * 16384, fbias + (20 + l) * 128,    // Cmat, pC
          deg, P, Qs, XU, nullptr);
    } else {
      mlp_fused<3><<<N / 64, 256, 0, stream>>>(Hagg, XU,
          fmats + 6 * 16384, fbias + 6 * 128,                  // Wf6, b2U6
          fmats + 13 * 16384, fbias + 13 * 128,                // Amat6 (head fold), pA6
          headW2T, headB2f,
          nullptr, nullptr,
          deg, nullptr, nullptr, nullptr, out32);
    }
  }

  loss_kernel<<<N / 256, 256, 0, stream>>>(out32, loc, yv, dflag, (float*)d_out, accp,
                                           ticket, NB, N / 256, 1.0f / 327680.0f);
}

// Round 15
// 478.715 us; speedup vs baseline: 1.2912x; 1.2912x over previous
//
#include <hip/hip_runtime.h>
#include <hip/hip_bf16.h>
#include <stdint.h>

#define HH 128

typedef __attribute__((ext_vector_type(8))) short short8;
typedef __attribute__((ext_vector_type(4))) float floatx4;

typedef __attribute__((address_space(3))) uint32_t lds_u32_t;
typedef const __attribute__((address_space(1))) uint32_t gbl_u32_t;

__device__ __forceinline__ void gl_lds16(const void* g, void* l) {
  __builtin_amdgcn_global_load_lds((gbl_u32_t*)g, (lds_u32_t*)l, 16, 0, 0);
}

__device__ __forceinline__ float bf2f(short v) {
  union { uint32_t u; float f; } x; x.u = ((uint32_t)(uint16_t)v) << 16; return x.f;
}
__device__ __forceinline__ short f2bf(float f) {
  union { float f; uint32_t u; } x; x.f = f;
  uint32_t r = x.u + 0x7fffu + ((x.u >> 16) & 1u);
  return (short)(r >> 16);
}
__device__ __forceinline__ float rdf(const void* p, int i, int fl) {
  return fl ? bf2f(((const short*)p)[i]) : ((const float*)p)[i];
}
__device__ __forceinline__ uint32_t packbf(float a, float b) {
  return (uint32_t)(uint16_t)f2bf(a) | ((uint32_t)(uint16_t)f2bf(b) << 16);
}

// ---------------- probe + zero kernel ----------------

__global__ void detect_zero(const int* __restrict__ eidx, int* iflag, int* dflag,
                            int* __restrict__ counts, float* accp, int* ticket,
                            const uint32_t* __restrict__ loc, int N) {
  int g = blockIdx.x * 256 + threadIdx.x;
  if (g < N) counts[g] = 0;
  if (blockIdx.x == 0) {
    __shared__ int nz, cnt;
    if (threadIdx.x == 0) { nz = 0; cnt = 0; *accp = 0.f; *ticket = 0; }
    __syncthreads();
    int any = 0;
    for (int i = threadIdx.x; i < 1024; i += 256) any |= (eidx[2 * i + 1] != 0);
    if (any) atomicOr(&nz, 1);
    uint32_t u = loc[threadIdx.x];
    int e = (u >> 7) & 0xFF;
    if (e >= 100 && e <= 140) atomicAdd(&cnt, 1);
    __syncthreads();
    if (threadIdx.x == 0) {
      *iflag = (nz == 0) ? 1 : 0;    // 1 => int64 layout
      *dflag = (cnt >= 192) ? 1 : 0; // 1 => bf16 tensors
    }
  }
}

// ---------------- prep kernels ----------------

__global__ void pad_input(const void* __restrict__ loc, const void* __restrict__ vel,
                          short* __restrict__ dst, const int* __restrict__ dflag) {
  int fl = *dflag;
  int idx = blockIdx.x * 256 + threadIdx.x;
  int j = idx & 63, i = idx >> 6;
  short v = 0;
  if (j < 60) {
    int f = j / 6, c = j % 6;
    float x = (c < 3) ? rdf(loc, (i * 10 + f) * 3 + c, fl)
                      : rdf(vel, (i * 10 + f) * 3 + (c - 3), fl);
    v = f2bf(x);
  }
  dst[idx] = v;
}

struct WPrep {
  const void* src[8];
  unsigned long long dstoff[8];
  int L[8], K[8], Nn[8], Kp[8], Np[8];
  int bstart[9];
};

__global__ void prep_w(WPrep a, short* __restrict__ wbase, const int* __restrict__ dflag) {
  int fl = *dflag;
  int b = blockIdx.x;
  int s = 0;
  while (b >= a.bstart[s + 1]) ++s;
  int idx = (b - a.bstart[s]) * 256 + threadIdx.x;
  int Kp = a.Kp[s], Np = a.Np[s], K = a.K[s], Nn = a.Nn[s];
  int tot = a.L[s] * Np * Kp;
  if (idx >= tot) return;
  int k = idx % Kp; int rest = idx / Kp; int n = rest % Np; int l = rest / Np;
  short v = 0;
  if (k < K && n < Nn) v = f2bf(rdf(a.src[s], (l * K + k) * Nn + n, fl));
  wbase[a.dstoff[s] + idx] = v;
}

struct BPrep {
  const void* src[8];
  int n[8];
  int estart[9];
};

__global__ void prep_b(BPrep a, float* __restrict__ bias, const int* __restrict__ dflag) {
  int fl = *dflag;
  int idx = blockIdx.x * 256 + threadIdx.x;
  if (idx >= a.estart[8]) return;
  int s = 0;
  while (idx >= a.estart[s + 1]) ++s;
  int j = idx - a.estart[s];
  bias[idx] = (j < a.n[s]) ? rdf(a.src[s], j, fl) : 0.0f;
}

// ---------------- fold precompute ----------------
// fmats (26 x 128x128, B-layout [n][k]):
//   m 0..6  : Wf_l   = msgW2_l @ updW1b_l
//   m 7..13 : Amat_l = updW2_l @ M1a_{l+1}   (l=6: updW2_6 @ headW1)
//   m 14..19: Bmat_l = updW2_l @ M1b_{l+1}
//   m 20..25: Cmat_l = updW2_l @ U1a_{l+1}
// fbias (26 x 128 fp32): b2U(0..6) | pA(7..13) | pB(14..19) | pC(20..25)

__global__ void fold_kernel(const short* __restrict__ msgW1T, const short* __restrict__ msgW2T,
                            const short* __restrict__ updW1T, const short* __restrict__ updW2T,
                            const short* __restrict__ headW1T,
                            const float* __restrict__ msgB1f, const float* __restrict__ msgB2f,
                            const float* __restrict__ updB1f, const float* __restrict__ updB2f,
                            const float* __restrict__ headB1f,
                            short* __restrict__ fmats, float* __restrict__ fbias) {
  if (blockIdx.x < 1664) {
    int idx = blockIdx.x * 256 + threadIdx.x;
    if (idx >= 26 * 16384) return;
    int k = idx & 127; int n = (idx >> 7) & 127; int m = idx >> 14;
    const short* w2;
    const short* rhs;
    if (m < 7) {
      w2 = msgW2T + m * 16384;
      rhs = updW1T + m * 32768 + n * 256 + 128;
    } else if (m < 14) {
      int l = m - 7;
      w2 = updW2T + l * 16384;
      rhs = (l < 6) ? (msgW1T + (l + 1) * 32768 + n * 256) : (headW1T + n * 128);
    } else if (m < 20) {
      int l = m - 14;
      w2 = updW2T + l * 16384;
      rhs = msgW1T + (l + 1) * 32768 + n * 256 + 128;
    } else {
      int l = m - 20;
      w2 = updW2T + l * 16384;
      rhs = updW1T + (l + 1) * 32768 + n * 256;
    }
    float s = 0.f;
    for (int j = 0; j < 128; ++j) s += bf2f(w2[j * 128 + k]) * bf2f(rhs[j]);
    fmats[idx] = f2bf(s);
  } else {
    int idx = (blockIdx.x - 1664) * 256 + threadIdx.x;
    if (idx >= 26 * 128) return;
    int n = idx & 127; int m = idx >> 7;
    float s = 0.f;
    if (m < 7) {
      const short* u1 = updW1T + m * 32768 + n * 256 + 128;
      for (int j = 0; j < 128; ++j) s += msgB2f[m * 128 + j] * bf2f(u1[j]);
    } else if (m < 14) {
      int l = m - 7;
      if (l < 6) {
        const short* m1 = msgW1T + (l + 1) * 32768 + n * 256;
        for (int j = 0; j < 128; ++j) s += updB2f[l * 128 + j] * bf2f(m1[j]);
        s += msgB1f[(l + 1) * 128 + n];
      } else {
        const short* h1 = headW1T + n * 128;
        for (int j = 0; j < 128; ++j) s += updB2f[6 * 128 + j] * bf2f(h1[j]);
        s += headB1f[n];
      }
    } else if (m < 20) {
      int l = m - 14;
      const short* m1 = msgW1T + (l + 1) * 32768 + n * 256 + 128;
      for (int j = 0; j < 128; ++j) s += updB2f[l * 128 + j] * bf2f(m1[j]);
    } else {
      int l = m - 20;
      const short* u1 = updW1T + (l + 1) * 32768 + n * 256;
      for (int j = 0; j < 128; ++j) s += updB2f[l * 128 + j] * bf2f(u1[j]);
      s += updB1f[(l + 1) * 128 + n];
    }
    fbias[m * 128 + n] = s;
  }
}

// ---------------- edge sort (counting sort by dst) ----------------

__global__ void hist_kernel(const int* __restrict__ eidx, const int* __restrict__ iflag,
                            int* __restrict__ counts, int E) {
  int e = blockIdx.x * 256 + threadIdx.x;
  if (e >= E) return;
  int fl = *iflag;
  int d = fl ? eidx[2 * (E + e)] : eidx[E + e];
  atomicAdd(&counts[d], 1);
}

__global__ void scan_bsum(const int* __restrict__ counts, int* __restrict__ bsums, int N) {
  int i = blockIdx.x * 256 + threadIdx.x;
  int v = (i < N) ? counts[i] : 0;
#pragma unroll
  for (int off = 1; off < 64; off <<= 1) v += __shfl_xor(v, off);
  __shared__ int ws4[4];
  if ((threadIdx.x & 63) == 0) ws4[threadIdx.x >> 6] = v;
  __syncthreads();
  if (threadIdx.x == 0) bsums[blockIdx.x] = ws4[0] + ws4[1] + ws4[2] + ws4[3];
}

__global__ void scan_final(const int* __restrict__ counts, const int* __restrict__ bsums,
                           int* __restrict__ row_start, int* __restrict__ cursor,
                           float* __restrict__ deg, int N, int E) {
  int t = threadIdx.x;
  __shared__ int shb[2];
  __shared__ int wsum[4];
  int v = (t < 128 && t < (int)blockIdx.x) ? bsums[t] : 0;
#pragma unroll
  for (int off = 1; off < 64; off <<= 1) v += __shfl_xor(v, off);
  if (t == 0) shb[0] = v;
  if (t == 64) shb[1] = v;
  int i = blockIdx.x * 256 + t;
  int c = (i < N) ? counts[i] : 0;
  int lane = t & 63, w = t >> 6;
  int x = c;
#pragma unroll
  for (int off = 1; off < 64; off <<= 1) {
    int u = __shfl_up(x, off);
    if (lane >= off) x += u;
  }
  if (lane == 63) wsum[w] = x;
  __syncthreads();
  int wpre = 0;
#pragma unroll
  for (int k = 0; k < 4; ++k)
    if (k < w) wpre += wsum[k];
  int excl = shb[0] + shb[1] + wpre + x - c;
  if (i < N) {
    row_start[i] = excl;
    cursor[i] = excl;
    deg[i] = (float)c;
  }
  if (i == N - 1) row_start[N] = E;
}

__global__ void scatter_kernel(const int* __restrict__ eidx, const int* __restrict__ iflag,
                               int* __restrict__ cursor, int* __restrict__ ssrc, int E) {
  int e = blockIdx.x * 256 + threadIdx.x;
  if (e >= E) return;
  int fl = *iflag;
  int d = fl ? eidx[2 * (E + e)] : eidx[E + e];
  int sv = fl ? eidx[2 * e] : eidx[e];
  int pos = atomicAdd(&cursor[d], 1);
  ssrc[pos] = sv;
}

// ---------------- edge aggregation: Hagg[d] = sum relu(P[d] + Q[src]) ----------------

__global__ __launch_bounds__(256)
void edge_agg(const uint32_t* __restrict__ Pp, const uint32_t* __restrict__ Qp,
              const int* __restrict__ ssrc, const int* __restrict__ row_start,
              uint32_t* __restrict__ Hagg, int Ntot) {
  int w = threadIdx.x >> 6, lane = threadIdx.x & 63;
  int d = blockIdx.x * 4 + w;
  if (d >= Ntot) return;
  uint32_t pv = Pp[(size_t)d * 64 + lane];
  float px = bf2f((short)(pv & 0xffff));
  float py = bf2f((short)(pv >> 16));
  int s0 = row_start[d], s1 = row_start[d + 1];
  float ax = 0.f, ay = 0.f;
  int e = s0;
  for (; e + 16 <= s1; e += 16) {
    int idx[16]; uint32_t q[16];
#pragma unroll
    for (int u = 0; u < 16; ++u) idx[u] = ssrc[e + u];
#pragma unroll
    for (int u = 0; u < 16; ++u) q[u] = Qp[(size_t)idx[u] * 64 + lane];
#pragma unroll
    for (int u = 0; u < 16; ++u) {
      float hx = px + bf2f((short)(q[u] & 0xffff));
      float hy = py + bf2f((short)(q[u] >> 16));
      ax += hx > 0.f ? hx : 0.f;
      ay += hy > 0.f ? hy : 0.f;
    }
  }
  if (e + 8 <= s1) {
    int idx[8]; uint32_t q[8];
#pragma unroll
    for (int u = 0; u < 8; ++u) idx[u] = ssrc[e + u];
#pragma unroll
    for (int u = 0; u < 8; ++u) q[u] = Qp[(size_t)idx[u] * 64 + lane];
#pragma unroll
    for (int u = 0; u < 8; ++u) {
      float hx = px + bf2f((short)(q[u] & 0xffff));
      float hy = py + bf2f((short)(q[u] >> 16));
      ax += hx > 0.f ? hx : 0.f;
      ay += hy > 0.f ? hy : 0.f;
    }
    e += 8;
  }
  if (e + 4 <= s1) {
    int idx[4]; uint32_t q[4];
#pragma unroll
    for (int u = 0; u < 4; ++u) idx[u] = ssrc[e + u];
#pragma unroll
    for (int u = 0; u < 4; ++u) q[u] = Qp[(size_t)idx[u] * 64 + lane];
#pragma unroll
    for (int u = 0; u < 4; ++u) {
      float hx = px + bf2f((short)(q[u] & 0xffff));
      float hy = py + bf2f((short)(q[u] >> 16));
      ax += hx > 0.f ? hx : 0.f;
      ay += hy > 0.f ? hy : 0.f;
    }
    e += 4;
  }
  if (e + 2 <= s1) {
    int i0 = ssrc[e], i1 = ssrc[e + 1];
    uint32_t q0 = Qp[(size_t)i0 * 64 + lane];
    uint32_t q1 = Qp[(size_t)i1 * 64 + lane];
    float hx = px + bf2f((short)(q0 & 0xffff)), hy = py + bf2f((short)(q0 >> 16));
    ax += hx > 0.f ? hx : 0.f; ay += hy > 0.f ? hy : 0.f;
    hx = px + bf2f((short)(q1 & 0xffff)); hy = py + bf2f((short)(q1 >> 16));
    ax += hx > 0.f ? hx : 0.f; ay += hy > 0.f ? hy : 0.f;
    e += 2;
  }
  if (e < s1) {
    int i0 = ssrc[e];
    uint32_t q0 = Qp[(size_t)i0 * 64 + lane];
    float hx = px + bf2f((short)(q0 & 0xffff));
    float hy = py + bf2f((short)(q0 >> 16));
    ax += hx > 0.f ? hx : 0.f;
    ay += hy > 0.f ? hy : 0.f;
  }
  Hagg[(size_t)d * 64 + lane] = packbf(ax, ay);
}

// ---------------- fused MLP helpers (M=64, 4 waves, 48 KB LDS) ----------------

__device__ __forceinline__ void write_aslots64(char* lds, const floatx4 v[2][4],
                                               int wr, int wc, int quad, int l16) {
#pragma unroll
  for (int mt = 0; mt < 2; ++mt) {
    int g = wr * 2 + mt;
#pragma unroll
    for (int nt = 0; nt < 4; ++nt) {
      int s2 = wc * 2 + (nt >> 1);
      int qc = (nt & 1) * 2 + (l16 >> 3);
      char* base = lds + (size_t)(s2 * 4 + g) * 1024 + 2 * (l16 & 7);
#pragma unroll
      for (int r = 0; r < 4; ++r)
        *(short*)(base + (quad * 4 + r + 16 * qc) * 16) = f2bf(v[mt][nt][r]);
    }
  }
}

template <int NT, int TS>
__device__ __forceinline__ void gemm64(const char* lds, int wr, int wc,
                                       floatx4 acc[2][NT], int lane) {
  const char* ldsB = lds + 16384;
#pragma unroll
  for (int s2 = 0; s2 < 4; ++s2) {
    short8 af[2];
#pragma unroll
    for (int mt = 0; mt < 2; ++mt)
      af[mt] = *(const short8*)(lds + (s2 * 4 + wr * 2 + mt) * 1024 + lane * 16);
    short8 bf[NT];
#pragma unroll
    for (int nt = 0; nt < NT; ++nt)
      bf[nt] = *(const short8*)(ldsB + (s2 * TS + wc * NT + nt) * 1024 + lane * 16);
#pragma unroll
    for (int mt = 0; mt < 2; ++mt)
#pragma unroll
      for (int nt = 0; nt < NT; ++nt)
        acc[mt][nt] = __builtin_amdgcn_mfma_f32_16x16x32_bf16(af[mt], bf[nt], acc[mt][nt], 0, 0, 0);
  }
}

__device__ __forceinline__ void stage128(const short* M, int stride, char* ldsB,
                                         int w, int lane, int quad, int l16) {
#pragma unroll
  for (int c = 0; c < 8; ++c) {
    int slot = w * 8 + c, s2 = slot >> 3, t = slot & 7;
    gl_lds16(M + (t * 16 + l16) * stride + s2 * 32 + quad * 8,
             ldsB + slot * 1024 + lane * 16);
  }
}

// ---------------- fused MLP kernel ----------------
// MODE 0: embed (in64 -> x0 in regs) then P0/Q0/XU0
// MODE 2: h = relu(XU + Hagg@Wf + deg*b2U) then P/Q/XU via folded mats
// MODE 3: h (layer 6) then head MLP -> out32

template <int MODE>
__global__ __launch_bounds__(256, 3)
void mlp_fused(const short* __restrict__ Ain, const short* __restrict__ XUin,
               const short* __restrict__ W1s, const float* __restrict__ b1s,
               const short* __restrict__ W2s, const float* __restrict__ b2s,
               const short* __restrict__ W3s, const float* __restrict__ b3s,
               const short* __restrict__ W4s, const float* __restrict__ b4s,
               const float* __restrict__ deg,
               short* __restrict__ Pout, short* __restrict__ Qout,
               short* __restrict__ XUout, float* __restrict__ out32) {
  __shared__ __align__(16) char lds[49152];
  char* ldsB = lds + 16384;

  const int tid = threadIdx.x;
  const int w = tid >> 6, lane = tid & 63;
  const int quad = lane >> 4, l16 = lane & 15;
  const int wr = w >> 1, wc = w & 1;
  const int R0 = blockIdx.x * 64;
  const int CB = wc * 64;

  floatx4 zero4 = {0.f, 0.f, 0.f, 0.f};
  floatx4 acc[2][4];

  if constexpr (MODE == 0) {
#pragma unroll
    for (int c = 0; c < 4; ++c) {
      int slot = w * 4 + c, s = slot >> 3, t = slot & 7;
      gl_lds16(W1s + (t * 16 + l16) * 64 + s * 32 + quad * 8,
               ldsB + slot * 1024 + lane * 16);
    }
    short8 afrag[2][2];
#pragma unroll
    for (int mt = 0; mt < 2; ++mt) {
      int m = R0 + wr * 32 + mt * 16 + l16;
      const short* pr = Ain + (size_t)m * 64;
#pragma unroll
      for (int s = 0; s < 2; ++s) afrag[s][mt] = *(const short8*)(pr + s * 32 + quad * 8);
    }
    float b1f[4], b2f[4], pa[4], pc[4];
#pragma unroll
    for (int t = 0; t < 4; ++t) {
      int col = CB + t * 16 + l16;
      b1f[t] = b1s[col]; b2f[t] = b2s[col]; pa[t] = b3s[col]; pc[t] = b4s[col];
    }
#pragma unroll
    for (int mt = 0; mt < 2; ++mt)
#pragma unroll
      for (int t = 0; t < 4; ++t) acc[mt][t] = zero4;
    __syncthreads();  // B1
#pragma unroll
    for (int s = 0; s < 2; ++s) {
      short8 bfrag[4];
#pragma unroll
      for (int nt = 0; nt < 4; ++nt)
        bfrag[nt] = *(const short8*)(ldsB + (s * 8 + wc * 4 + nt) * 1024 + lane * 16);
#pragma unroll
      for (int mt = 0; mt < 2; ++mt)
#pragma unroll
        for (int nt = 0; nt < 4; ++nt)
          acc[mt][nt] = __builtin_amdgcn_mfma_f32_16x16x32_bf16(afrag[s][mt], bfrag[nt], acc[mt][nt], 0, 0, 0);
    }
    __syncthreads();  // B2
    stage128(W2s, 128, ldsB, w, lane, quad, l16);  // embW2
    {
      floatx4 hv[2][4];
#pragma unroll
      for (int mt = 0; mt < 2; ++mt)
#pragma unroll
        for (int nt = 0; nt < 4; ++nt)
#pragma unroll
          for (int r = 0; r < 4; ++r) {
            float h = acc[mt][nt][r] + b1f[nt];
            hv[mt][nt][r] = h > 0.f ? h : 0.f;
          }
      write_aslots64(lds, hv, wr, wc, quad, l16);
    }
    __syncthreads();  // B3
    floatx4 accx[2][4];
#pragma unroll
    for (int mt = 0; mt < 2; ++mt)
#pragma unroll
      for (int t = 0; t < 4; ++t) accx[mt][t] = zero4;
    gemm64<4, 8>(lds, wr, wc, accx, lane);
    floatx4 xv[2][4];
#pragma unroll
    for (int mt = 0; mt < 2; ++mt)
#pragma unroll
      for (int nt = 0; nt < 4; ++nt)
#pragma unroll
        for (int r = 0; r < 4; ++r)
          xv[mt][nt][r] = accx[mt][nt][r] + b2f[nt];
    __syncthreads();  // B4
    write_aslots64(lds, xv, wr, wc, quad, l16);
    stage128(W3s, 256, ldsB, w, lane, quad, l16);  // M1a_0
    __syncthreads();  // B5
    floatx4 ap[2][4];
#pragma unroll
    for (int mt = 0; mt < 2; ++mt)
#pragma unroll
      for (int t = 0; t < 4; ++t) ap[mt][t] = zero4;
    gemm64<4, 8>(lds, wr, wc, ap, lane);
#pragma unroll
    for (int mt = 0; mt < 2; ++mt)
#pragma unroll
      for (int nt = 0; nt < 4; ++nt) {
        int col = CB + nt * 16 + l16;
#pragma unroll
        for (int r = 0; r < 4; ++r) {
          int row = R0 + wr * 32 + mt * 16 + quad * 4 + r;
          Pout[(size_t)row * HH + col] = f2bf(ap[mt][nt][r] + pa[nt]);
        }
      }
    __syncthreads();  // B6
    stage128(W3s + 128, 256, ldsB, w, lane, quad, l16);  // M1b_0
    __syncthreads();  // B7
    floatx4 aq[2][4];
#pragma unroll
    for (int mt = 0; mt < 2; ++mt)
#pragma unroll
      for (int t = 0; t < 4; ++t) aq[mt][t] = zero4;
    gemm64<4, 8>(lds, wr, wc, aq, lane);
#pragma unroll
    for (int mt = 0; mt < 2; ++mt)
#pragma unroll
      for (int nt = 0; nt < 4; ++nt) {
        int col = CB + nt * 16 + l16;
#pragma unroll
        for (int r = 0; r < 4; ++r) {
          int row = R0 + wr * 32 + mt * 16 + quad * 4 + r;
          Qout[(size_t)row * HH + col] = f2bf(aq[mt][nt][r]);
        }
      }
    __syncthreads();  // B8
    stage128(W4s, 256, ldsB, w, lane, quad, l16);  // U1a_0
    __syncthreads();  // B9
    floatx4 au[2][4];
#pragma unroll
    for (int mt = 0; mt < 2; ++mt)
#pragma unroll
      for (int t = 0; t < 4; ++t) au[mt][t] = zero4;
    gemm64<4, 8>(lds, wr, wc, au, lane);
#pragma unroll
    for (int mt = 0; mt < 2; ++mt)
#pragma unroll
      for (int nt = 0; nt < 4; ++nt) {
        int col = CB + nt * 16 + l16;
#pragma unroll
        for (int r = 0; r < 4; ++r) {
          int row = R0 + wr * 32 + mt * 16 + quad * 4 + r;
          XUout[(size_t)row * HH + col] = f2bf(au[mt][nt][r] + pc[nt]);
        }
      }
    return;
  } else {
    // --- stage Wf; Hagg frags; acc init = XU + deg*b2U ---
    stage128(W1s, 128, ldsB, w, lane, quad, l16);
    short8 hfrag[4][2];
#pragma unroll
    for (int mt = 0; mt < 2; ++mt) {
      int m = R0 + wr * 32 + mt * 16 + l16;
      const short* pr = Ain + (size_t)m * HH;
#pragma unroll
      for (int s = 0; s < 4; ++s) hfrag[s][mt] = *(const short8*)(pr + s * 32 + quad * 8);
    }
    float b2u[4], pa[4], pb[4], pc[4];
#pragma unroll
    for (int t = 0; t < 4; ++t) {
      int col = CB + t * 16 + l16;
      b2u[t] = b1s[col];
      pa[t] = b2s[col];
      if constexpr (MODE == 2) { pb[t] = b3s[col]; pc[t] = b4s[col]; }
    }
    float dvals[2][4];
#pragma unroll
    for (int mt = 0; mt < 2; ++mt)
#pragma unroll
      for (int r = 0; r < 4; ++r)
        dvals[mt][r] = deg[R0 + wr * 32 + mt * 16 + quad * 4 + r];
#pragma unroll
    for (int mt = 0; mt < 2; ++mt)
#pragma unroll
      for (int nt = 0; nt < 4; ++nt) {
        int col = CB + nt * 16 + l16;
#pragma unroll
        for (int r = 0; r < 4; ++r) {
          int row = R0 + wr * 32 + mt * 16 + quad * 4 + r;
          acc[mt][nt][r] = bf2f(XUin[(size_t)row * HH + col]) + dvals[mt][r] * b2u[nt];
        }
      }
    __syncthreads();  // B1
    // GEMM1: Hagg @ Wf
#pragma unroll
    for (int s = 0; s < 4; ++s) {
      short8 bfrag[4];
#pragma unroll
      for (int nt = 0; nt < 4; ++nt)
        bfrag[nt] = *(const short8*)(ldsB + (s * 8 + wc * 4 + nt) * 1024 + lane * 16);
#pragma unroll
      for (int mt = 0; mt < 2; ++mt)
#pragma unroll
        for (int nt = 0; nt < 4; ++nt)
          acc[mt][nt] = __builtin_amdgcn_mfma_f32_16x16x32_bf16(hfrag[s][mt], bfrag[nt], acc[mt][nt], 0, 0, 0);
    }
    __syncthreads();  // B2
    stage128(W2s, 128, ldsB, w, lane, quad, l16);  // Amat
    {
      floatx4 hv[2][4];
#pragma unroll
      for (int mt = 0; mt < 2; ++mt)
#pragma unroll
        for (int nt = 0; nt < 4; ++nt)
#pragma unroll
          for (int r = 0; r < 4; ++r) {
            float h = acc[mt][nt][r];
            hv[mt][nt][r] = h > 0.f ? h : 0.f;
          }
      write_aslots64(lds, hv, wr, wc, quad, l16);
    }
    __syncthreads();  // B3
    floatx4 ap[2][4];
#pragma unroll
    for (int mt = 0; mt < 2; ++mt)
#pragma unroll
      for (int t = 0; t < 4; ++t) ap[mt][t] = zero4;
    gemm64<4, 8>(lds, wr, wc, ap, lane);

    if constexpr (MODE == 2) {
      // P
#pragma unroll
      for (int mt = 0; mt < 2; ++mt)
#pragma unroll
        for (int nt = 0; nt < 4; ++nt) {
          int col = CB + nt * 16 + l16;
#pragma unroll
          for (int r = 0; r < 4; ++r) {
            int row = R0 + wr * 32 + mt * 16 + quad * 4 + r;
            Pout[(size_t)row * HH + col] = f2bf(ap[mt][nt][r] + pa[nt]);
          }
        }
      __syncthreads();  // B4
      stage128(W3s, 128, ldsB, w, lane, quad, l16);  // Bmat
      __syncthreads();  // B5
      floatx4 aq[2][4];
#pragma unroll
      for (int mt = 0; mt < 2; ++mt)
#pragma unroll
        for (int t = 0; t < 4; ++t) aq[mt][t] = zero4;
      gemm64<4, 8>(lds, wr, wc, aq, lane);
#pragma unroll
      for (int mt = 0; mt < 2; ++mt)
#pragma unroll
        for (int nt = 0; nt < 4; ++nt) {
          int col = CB + nt * 16 + l16;
#pragma unroll
          for (int r = 0; r < 4; ++r) {
            int row = R0 + wr * 32 + mt * 16 + quad * 4 + r;
            Qout[(size_t)row * HH + col] = f2bf(aq[mt][nt][r] + pb[nt]);
          }
        }
      __syncthreads();  // B6
      stage128(W4s, 128, ldsB, w, lane, quad, l16);  // Cmat
      __syncthreads();  // B7
      floatx4 au[2][4];
#pragma unroll
      for (int mt = 0; mt < 2; ++mt)
#pragma unroll
        for (int t = 0; t < 4; ++t) au[mt][t] = zero4;
      gemm64<4, 8>(lds, wr, wc, au, lane);
#pragma unroll
      for (int mt = 0; mt < 2; ++mt)
#pragma unroll
        for (int nt = 0; nt < 4; ++nt) {
          int col = CB + nt * 16 + l16;
#pragma unroll
          for (int r = 0; r < 4; ++r) {
            int row = R0 + wr * 32 + mt * 16 + quad * 4 + r;
            XUout[(size_t)row * HH + col] = f2bf(au[mt][nt][r] + pc[nt]);
          }
        }
    } else {
      // MODE 3: head hidden = relu(ap + pa6)
      floatx4 h2[2][4];
#pragma unroll
      for (int mt = 0; mt < 2; ++mt)
#pragma unroll
        for (int nt = 0; nt < 4; ++nt)
#pragma unroll
          for (int r = 0; r < 4; ++r) {
            float h = ap[mt][nt][r] + pa[nt];
            h2[mt][nt][r] = h > 0.f ? h : 0.f;
          }
      __syncthreads();  // B4
      write_aslots64(lds, h2, wr, wc, quad, l16);
      // stage headW2 (32x128): 8 slots, 2 per wave
#pragma unroll
      for (int c = 0; c < 2; ++c) {
        int slot = w * 2 + c, s2 = slot >> 1, t = slot & 1;
        gl_lds16(W3s + (t * 16 + l16) * 128 + s2 * 32 + quad * 8,
                 ldsB + slot * 1024 + lane * 16);
      }
      __syncthreads();  // B5
      floatx4 acco[2][1];
#pragma unroll
      for (int mt = 0; mt < 2; ++mt) acco[mt][0] = zero4;
      gemm64<1, 2>(lds, wr, wc, acco, lane);
      float ob = b3s[wc * 16 + l16];
#pragma unroll
      for (int mt = 0; mt < 2; ++mt) {
        int col = wc * 16 + l16;
#pragma unroll
        for (int r = 0; r < 4; ++r) {
          int row = R0 + wr * 32 + mt * 16 + quad * 4 + r;
          out32[(size_t)row * 32 + col] = acco[mt][0][r] + ob;
        }
      }
    }
  }
}

// ---------------- loss (fused final reduction via ticket) ----------------

__global__ void loss_kernel(const float* __restrict__ out32, const void* __restrict__ loc,
                            const void* __restrict__ yv, const int* __restrict__ dflag,
                            float* __restrict__ out, float* __restrict__ acc,
                            int* __restrict__ ticket, int NB, int nblocks, float inv) {
  int fl = *dflag;
  int i = blockIdx.x * 256 + threadIdx.x;
  const float* o = out32 + (size_t)i * 32;
  float dsum = 0.f, fde = 0.f;
#pragma unroll
  for (int f = 0; f < 10; ++f) {
    float dx = o[f * 3 + 0] + rdf(loc, i * 30 + f * 3 + 0, fl) - rdf(yv, i * 30 + f * 3 + 0, fl);
    float dy = o[f * 3 + 1] + rdf(loc, i * 30 + f * 3 + 1, fl) - rdf(yv, i * 30 + f * 3 + 1, fl);
    float dz = o[f * 3 + 2] + rdf(loc, i * 30 + f * 3 + 2, fl) - rdf(yv, i * 30 + f * 3 + 2, fl);
    float d = sqrtf(dx * dx + dy * dy + dz * dz);
    dsum += d;
    if (f == 9) fde = d;
  }
#pragma unroll
  for (int m = 1; m < 16; m <<= 1) {
    dsum += __shfl_xor(dsum, m);
    fde += __shfl_xor(fde, m);
  }
  if ((threadIdx.x & 15) == 0) {
    int b = i >> 4;
    out[1 + b] = dsum / 160.0f;
    out[1 + NB + b] = fde / 16.0f;
    unsafeAtomicAdd(acc, dsum);
  }
  __threadfence();
  __syncthreads();
  if (threadIdx.x == 0) {
    int old = atomicAdd(ticket, 1);
    if (old == nblocks - 1) {
      float v = unsafeAtomicAdd(acc, 0.0f);
      out[0] = v * inv;
    }
  }
}

// ---------------- host ----------------

extern "C" void kernel_launch(void* const* d_in, const int* in_sizes, int n_in,
                              void* d_out, int out_size, void* d_ws, size_t ws_size,
                              hipStream_t stream) {
  const void* loc = d_in[0];
  const void* vel = d_in[1];
  const void* yv = d_in[2];
  const int* eidx = (const int*)d_in[3];

  const int N = in_sizes[0] / 30;  // 32768
  const int E = in_sizes[3] / 2;   // 524288
  const int L = 7;
  const int NB = N / 16;

  const size_t MB = 1024 * 1024;
  char* ws = (char*)d_ws;
  short* XU = (short*)ws;                    // N*128 bf16   [0,8)MB
  short* P = (short*)(ws + 8 * MB);          // N*128 bf16
  short* Qs = (short*)(ws + 24 * MB);        // N*128 bf16
  short* Hagg = (short*)(ws + 32 * MB);      // N*128 bf16
  short* fmats = (short*)(ws + 40 * MB);     // 26*16384 bf16 (832KB)
  int* bsums = (int*)(ws + 41 * MB);
  short* wbase = (short*)(ws + 48 * MB);
  const unsigned long long OFF_EMBW1 = 0;
  const unsigned long long OFF_EMBW2 = 8192;
  const unsigned long long OFF_HEADW1 = 24576;
  const unsigned long long OFF_HEADW2 = 40960;
  const unsigned long long OFF_MSGW1 = 45056;
  const unsigned long long OFF_MSGW2 = 274432;
  const unsigned long long OFF_UPDW1 = 389120;
  const unsigned long long OFF_UPDW2 = 618496;
  short* embW1T = wbase + OFF_EMBW1;
  short* embW2T = wbase + OFF_EMBW2;
  short* headW1T = wbase + OFF_HEADW1;
  short* headW2T = wbase + OFF_HEADW2;
  short* msgW1T = wbase + OFF_MSGW1;
  short* msgW2T = wbase + OFF_MSGW2;
  short* updW1T = wbase + OFF_UPDW1;
  short* updW2T = wbase + OFF_UPDW2;
  float* bias = (float*)(ws + 49 * MB + 512 * 1024);
  float* embB1f = bias;
  float* embB2f = bias + 128;
  float* msgB1f = bias + 256;
  float* msgB2f = bias + 1152;
  float* updB1f = bias + 2048;
  float* updB2f = bias + 2944;
  float* headB1f = bias + 3840;
  float* headB2f = bias + 3968;
  float* fbias = (float*)(ws + 49 * MB + 640 * 1024);  // 26*128 fp32
  int* counts = (int*)(ws + 49 * MB + 768 * 1024);
  int* row_start = (int*)(ws + 50 * MB);
  int* cursor = (int*)(ws + 50 * MB + 256 * 1024);
  float* deg = (float*)(ws + 50 * MB + 512 * 1024);
  int* iflag = (int*)(ws + 50 * MB + 768 * 1024);
  int* dflag = iflag + 16;
  float* accp = (float*)(iflag + 32);
  int* ticket = iflag + 48;
  int* ssrc = (int*)(ws + 51 * MB);
  short* in64 = (short*)(ws + 53 * MB);
  float* out32 = (float*)(ws + 57 * MB);

  const int NBLK = (N + 255) / 256;  // 128

  detect_zero<<<NBLK, 256, 0, stream>>>(eidx, iflag, dflag, counts, accp, ticket,
                                        (const uint32_t*)loc, N);
  hist_kernel<<<(E + 255) / 256, 256, 0, stream>>>(eidx, iflag, counts, E);
  scan_bsum<<<NBLK, 256, 0, stream>>>(counts, bsums, N);
  scan_final<<<NBLK, 256, 0, stream>>>(counts, bsums, row_start, cursor, deg, N, E);
  scatter_kernel<<<(E + 255) / 256, 256, 0, stream>>>(eidx, iflag, cursor, ssrc, E);

  pad_input<<<(N * 64) / 256, 256, 0, stream>>>(loc, vel, in64, dflag);

  {
    WPrep a;
    const void* srcs[8] = {d_in[5], d_in[7], d_in[17], d_in[19],
                           d_in[9], d_in[11], d_in[13], d_in[15]};
    unsigned long long offs[8] = {OFF_EMBW1, OFF_EMBW2, OFF_HEADW1, OFF_HEADW2,
                                  OFF_MSGW1, OFF_MSGW2, OFF_UPDW1, OFF_UPDW2};
    int Ls[8] = {1, 1, 1, 1, 7, 7, 7, 7};
    int Ks[8] = {60, 128, 128, 128, 256, 128, 256, 128};
    int Ns[8] = {128, 128, 128, 30, 128, 128, 128, 128};
    int Kps[8] = {64, 128, 128, 128, 256, 128, 256, 128};
    int Nps[8] = {128, 128, 128, 32, 128, 128, 128, 128};
    int cum = 0;
    for (int s = 0; s < 8; ++s) {
      a.src[s] = srcs[s]; a.dstoff[s] = offs[s];
      a.L[s] = Ls[s]; a.K[s] = Ks[s]; a.Nn[s] = Ns[s]; a.Kp[s] = Kps[s]; a.Np[s] = Nps[s];
      a.bstart[s] = cum;
      cum += (Ls[s] * Nps[s] * Kps[s] + 255) / 256;
    }
    a.bstart[8] = cum;
    prep_w<<<cum, 256, 0, stream>>>(a, wbase, dflag);
  }
  {
    BPrep a;
    const void* srcs[8] = {d_in[6], d_in[8], d_in[10], d_in[12],
                           d_in[14], d_in[16], d_in[18], d_in[20]};
    int ns[8] = {128, 128, 896, 896, 896, 896, 128, 30};
    int es[9] = {0, 128, 256, 1152, 2048, 2944, 3840, 3968, 4000};
    for (int s = 0; s < 8; ++s) { a.src[s] = srcs[s]; a.n[s] = ns[s]; a.estart[s] = es[s]; }
    a.estart[8] = es[8];
    prep_b<<<16, 256, 0, stream>>>(a, bias, dflag);
  }

  fold_kernel<<<1664 + 13, 256, 0, stream>>>(msgW1T, msgW2T, updW1T, updW2T, headW1T,
                                             msgB1f, msgB2f, updB1f, updB2f, headB1f,
                                             fmats, fbias);

  // embed -> P0/Q0/XU0
  mlp_fused<0><<<N / 64, 256, 0, stream>>>(in64, nullptr,
      embW1T, embB1f, embW2T, embB2f,
      msgW1T, msgB1f, updW1T, updB1f,
      nullptr, P, Qs, XU, nullptr);

  for (int l = 0; l < L; ++l) {
    edge_agg<<<(N + 3) / 4, 256, 0, stream>>>((const uint32_t*)P, (const uint32_t*)Qs,
                                              ssrc, row_start, (uint32_t*)Hagg, N);
    if (l < L - 1) {
      mlp_fused<2><<<N / 64, 256, 0, stream>>>(Hagg, XU,
          fmats + l * 16384, fbias + l * 128,                  // Wf, b2U
          fmats + (7 + l) * 16384, fbias + (7 + l) * 128,      // Amat, pA
          fmats + (14 + l) * 16384, fbias + (14 + l) * 128,    // Bmat, pB
          fmats + (20 + l) * 16384, fbias + (20 + l) * 128,    // Cmat, pC
          deg, P, Qs, XU, nullptr);
    } else {
      mlp_fused<3><<<N / 64, 256, 0, stream>>>(Hagg, XU,
          fmats + 6 * 16384, fbias + 6 * 128,                  // Wf6, b2U6
          fmats + 13 * 16384, fbias + 13 * 128,                // Amat6 (head fold), pA6
          headW2T, headB2f,
          nullptr, nullptr,
          deg, nullptr, nullptr, nullptr, out32);
    }
  }

  loss_kernel<<<N / 256, 256, 0, stream>>>(out32, loc, yv, dflag, (float*)d_out, accp,
                                           ticket, NB, N / 256, 1.0f / 327680.0f);
}